// Round 11
// baseline (505.107 us; speedup 1.0000x reference)
//
#include <hip/hip_runtime.h>
#include <hip/hip_bf16.h>
#include <math.h>

#define N_EXPERTS 8
#define TOPK      2
#define IN_DIM    512
#define HID_DIM   1024
#define OUT_DIM   512
#define B_TOKENS  16384
#define NPAIRS    (B_TOKENS * TOPK)   // 32768 token-expert pairs (fixed!)
#define MAX_RB    264                 // max 128-row blocks after per-expert pad
#define MAX_ROWS  (MAX_RB * 128)      // 33792

typedef __attribute__((ext_vector_type(8))) short short8;   // 8 bf16
typedef __attribute__((ext_vector_type(4))) float floatx4;

// ---- workspace layout (bytes) ----
#define WS_CNT     0          // 8 int
#define WS_CURSOR  32         // 8 int
#define WS_TKIDX   1280       // 32768 int
#define WS_TKW     132352     // 32768 float
#define WS_ROWS    263424     // 33792 int
#define WS_WPOS    398592     // 33792 float
#define WS_W1T     533760     // 8*1024*512 bf16 = 8 MB
#define WS_W2T     8922368    // 8*512*1024 bf16 = 8 MB
#define WS_XG      17310976   // 33792*512 bf16  = 34.6 MB
#define WS_H       51913984   // 33792*1024 bf16 = 69.2 MB

__device__ __forceinline__ short f2bf(float f) {
  unsigned u = __float_as_uint(f);
  unsigned r = (u + 0x7fffu + ((u >> 16) & 1u)) >> 16;  // RNE
  return (short)r;
}

// ---------------- front: weight transposes (blocks 0..8191) + gate (blocks 8192..9215) ----------------
__global__ __launch_bounds__(256) void front_kernel(const float* __restrict__ w1,
                                                    short* __restrict__ w1t,
                                                    const float* __restrict__ w2,
                                                    short* __restrict__ w2t,
                                                    const float* __restrict__ x,
                                                    const float* __restrict__ gw,
                                                    const float* __restrict__ gb,
                                                    int* __restrict__ tkidx,
                                                    float* __restrict__ tkw,
                                                    int* __restrict__ cnt) {
  __shared__ float tile[32][33];
  __shared__ int lds_cnt[N_EXPERTS];
  const int b = blockIdx.x;
  if (b < 8192) {
    const int z = b >> 9, lin = b & 511;
    const int e = z & 7, which = z >> 3;
    const int R = which ? HID_DIM : IN_DIM;
    const int C = which ? OUT_DIM : HID_DIM;
    const float* src = (which ? w2 : w1) + (size_t)e * R * C;
    short* dst = (which ? w2t : w1t) + (size_t)e * R * C;
    const int bx = which ? (lin & 15) : (lin & 31);
    const int by = which ? (lin >> 4) : (lin >> 5);
    const int r0 = by * 32, c0 = bx * 32;
    const int tr = threadIdx.x >> 5, tc = threadIdx.x & 31;
#pragma unroll
    for (int j = 0; j < 4; ++j)
      tile[tr + j * 8][tc] = src[(size_t)(r0 + tr + j * 8) * C + c0 + tc];
    __syncthreads();
#pragma unroll
    for (int j = 0; j < 4; ++j)
      dst[(size_t)(c0 + tr + j * 8) * R + r0 + tc] = f2bf(tile[tc][tr + j * 8]);
    return;
  }
  // ---- gate ----
  const int bid = b - 8192;
  if (threadIdx.x < N_EXPERTS) lds_cnt[threadIdx.x] = 0;
  __syncthreads();
  int w = threadIdx.x >> 6, lane = threadIdx.x & 63;
#pragma unroll 1
  for (int q = 0; q < 4; ++q) {
    int t = bid * 16 + w * 4 + q;
    float s[8] = {0.f, 0.f, 0.f, 0.f, 0.f, 0.f, 0.f, 0.f};
#pragma unroll
    for (int it = 0; it < 8; ++it) {
      int i = it * 64 + lane;
      float xv = x[(size_t)t * IN_DIM + i];
      const float4* gwr = (const float4*)(gw + (size_t)i * 8);
      float4 g0 = gwr[0], g1 = gwr[1];
      s[0] += xv * g0.x; s[1] += xv * g0.y; s[2] += xv * g0.z; s[3] += xv * g0.w;
      s[4] += xv * g1.x; s[5] += xv * g1.y; s[6] += xv * g1.z; s[7] += xv * g1.w;
    }
#pragma unroll
    for (int off = 32; off > 0; off >>= 1) {
#pragma unroll
      for (int j = 0; j < 8; ++j) s[j] += __shfl_xor(s[j], off);
    }
    if (lane == 0) {
      float v[8];
#pragma unroll
      for (int j = 0; j < 8; ++j) v[j] = s[j] + gb[j];
      int i1 = 0; float v1 = v[0];
#pragma unroll
      for (int j = 1; j < 8; ++j) if (v[j] > v1) { v1 = v[j]; i1 = j; }
      int i2 = -1; float v2 = -1e30f;
#pragma unroll
      for (int j = 0; j < 8; ++j) if (j != i1 && v[j] > v2) { v2 = v[j]; i2 = j; }
      float ex = expf(v2 - v1);
      float wa = 1.0f / (1.0f + ex);
      tkidx[t * 2] = i1; tkidx[t * 2 + 1] = i2;
      tkw[t * 2] = wa;  tkw[t * 2 + 1] = ex * wa;
      atomicAdd(&lds_cnt[i1], 1); atomicAdd(&lds_cnt[i2], 1);
    }
  }
  __syncthreads();
  if (threadIdx.x < N_EXPERTS) atomicAdd(&cnt[threadIdx.x], lds_cnt[threadIdx.x]);
}

// ---------------- rank: position assignment + pad zero + aux (local offsets from cnt) ----------------
__global__ __launch_bounds__(1024) void rank_kernel(const int* __restrict__ tkidx,
                                                    const float* __restrict__ tkw,
                                                    const int* __restrict__ cnt,
                                                    int* __restrict__ cursor,
                                                    int* __restrict__ rows,
                                                    float* __restrict__ wpos,
                                                    float* __restrict__ aux_out) {
  __shared__ int wave_cnt[16][N_EXPERTS];
  __shared__ int wave_base[16][N_EXPERTS];
  __shared__ int blk_base[N_EXPERTS];
  const int tid = threadIdx.x, lane = tid & 63, w = tid >> 6;
  int c[N_EXPERTS], off[N_EXPERTS + 1];
  off[0] = 0;
#pragma unroll
  for (int j = 0; j < N_EXPERTS; ++j) {
    c[j] = cnt[j];
    off[j + 1] = off[j] + ((c[j] + 127) & ~127);
  }
  const int pr = blockIdx.x * 1024 + tid;
  const int e = tkidx[pr];
  int myrank = 0;
#pragma unroll
  for (int ei = 0; ei < N_EXPERTS; ++ei) {
    unsigned long long m = __ballot(e == ei);
    if (e == ei) myrank = __popcll(m & ((1ull << lane) - 1ull));
    if (lane == 0) wave_cnt[w][ei] = __popcll(m);
  }
  __syncthreads();
  if (tid < N_EXPERTS) {
    int base = 0;
#pragma unroll
    for (int ww = 0; ww < 16; ++ww) { wave_base[ww][tid] = base; base += wave_cnt[ww][tid]; }
    blk_base[tid] = atomicAdd(&cursor[tid], base);
  }
  __syncthreads();
  const int p = off[e] + blk_base[e] + wave_base[w][e] + myrank;
  rows[p] = pr >> 1;
  wpos[p] = tkw[pr];
  if (blockIdx.x == 0) {
    if (tid < N_EXPERTS * 128) {
      int ee = tid >> 7, sl = tid & 127;
      int pp = off[ee] + c[ee] + sl;
      if (pp < off[ee + 1]) { rows[pp] = 0; wpos[pp] = 0.f; }
    }
    if (tid == 0) {
      float aux = 0.f;
#pragma unroll
      for (int j = 0; j < N_EXPERTS; ++j) {
        float d = (float)c[j] / (float)NPAIRS - 1.0f / N_EXPERTS;
        aux += d * d;
      }
      aux_out[0] = aux / N_EXPERTS;
    }
  }
}

// ---------------- copy: gather x rows (fp32->bf16) into grouped order ----------------
__global__ __launch_bounds__(256) void copy_kernel(const float* __restrict__ x,
                                                   const int* __restrict__ rows,
                                                   const int* __restrict__ cnt,
                                                   short* __restrict__ xg) {
  const int w = threadIdx.x >> 6, lane = threadIdx.x & 63;
  int total = 0;
#pragma unroll
  for (int j = 0; j < N_EXPERTS; ++j) total += (cnt[j] + 127) & ~127;
  const int p = blockIdx.x * 4 + w;
  if (p >= total) return;
  const int t = rows[p];
  const floatx4* xr = (const floatx4*)(x + (size_t)t * IN_DIM);
  floatx4 a = xr[lane * 2], b = xr[lane * 2 + 1];
  short8 o;
  o[0] = f2bf(a[0]); o[1] = f2bf(a[1]); o[2] = f2bf(a[2]); o[3] = f2bf(a[3]);
  o[4] = f2bf(b[0]); o[5] = f2bf(b[1]); o[6] = f2bf(b[2]); o[7] = f2bf(b[3]);
  *(short8*)(xg + (size_t)p * IN_DIM + lane * 8) = o;
}

// ---------------- grouped GEMM: 128x128 tile, NO LDS — direct global fragment loads ----------------
// m177 ablation: staging = 90% of GEMM cost, and 10 rounds of schedule surgery on the
// staged structure moved 118 -> 114us only. Both operands are L2/L3-resident after the
// XCD swizzle, and the MFMA fragment layout is DIRECTLY loadable from row-major global:
//   A-frag (t,kk): A[row0 + wm*64 + t*16 + mlow][k + quad*8 .. +8]    (16B/lane)
//   B-frag (t,kk): B[e][n0 + wn*64 + t*16 + mlow][k + quad*8 .. +8]
// One frag instruction = 16 rows x 64B dense segments (same coalescing shape as the old
// staging loads). Waves sharing a fragment (same wm / same wn) hit L1 on the repeat.
// No LDS, no barriers, no ds ops -> compiler pipelines loads/MFMA freely (m97 lesson),
// latency hidden by ~4 blocks/CU TLP (no LDS limit, VGPR ~120).
// MODE 0: H = gelu(A @ W1[e] + b1[e]) -> bf16     (KD=512,  ND=1024)
// MODE 1: atomicAdd(out[tok], w * (A @ W2[e] + b2[e]))   (KD=1024, ND=512)
template <int KD, int ND, int MODE>
__global__ __launch_bounds__(256) void moe_gemm(const short* __restrict__ Amat,
                                                const short* __restrict__ Bmat,
                                                const float* __restrict__ bias,
                                                const int* __restrict__ cnt,
                                                const int* __restrict__ rows,
                                                const float* __restrict__ wpos,
                                                short* __restrict__ Hout,
                                                float* __restrict__ Oout) {
  // --- XCD-gather swizzle ---
  const int nwg = gridDim.x * gridDim.y;
  const int lin = blockIdx.x + blockIdx.y * gridDim.x;
  const int newlin = (lin & 7) * (nwg >> 3) + (lin >> 3);
  const int nb = newlin % gridDim.x;
  const int rb = newlin / gridDim.x;
  const int row0 = rb * 128;

  // --- local expert id from cnt ---
  int off = 0, e = -1;
#pragma unroll
  for (int j = 0; j < N_EXPERTS; ++j) {
    int nxt = off + ((cnt[j] + 127) & ~127);
    if (row0 >= off && row0 < nxt) e = j;
    off = nxt;
  }
  if (e < 0) return;

  const int n0 = nb * 128;
  const int tid = threadIdx.x;
  const int lane = tid & 63, w = tid >> 6;
  const int wm = w & 1, wn = w >> 1;
  const int mlow = lane & 15, quad = lane >> 4;

  floatx4 acc[4][4] = {};

  // per-lane fragment base addresses (row-major, 16B slices)
  const short* gA = Amat + (size_t)(row0 + wm * 64 + mlow) * KD + quad * 8;
  const short* gB = Bmat + (size_t)e * ND * KD + (size_t)(n0 + wn * 64 + mlow) * KD + quad * 8;

#pragma unroll 2
  for (int k = 0; k < KD; k += 32) {
    short8 a[4], b[4];
#pragma unroll
    for (int t = 0; t < 4; ++t) {
      a[t] = *(const short8*)(gA + (size_t)t * 16 * KD + k);
      b[t] = *(const short8*)(gB + (size_t)t * 16 * KD + k);
    }
#pragma unroll
    for (int ti = 0; ti < 4; ++ti)
#pragma unroll
      for (int tj = 0; tj < 4; ++tj)
        acc[ti][tj] = __builtin_amdgcn_mfma_f32_16x16x32_bf16(a[ti], b[tj], acc[ti][tj], 0, 0, 0);
  }

  if (MODE == 0) {
    const float* be = bias + (size_t)e * ND;
#pragma unroll
    for (int ti = 0; ti < 4; ++ti) {
      int gr = row0 + wm * 64 + ti * 16 + quad * 4;
#pragma unroll
      for (int tj = 0; tj < 4; ++tj) {
        int gc = n0 + wn * 64 + tj * 16 + mlow;
        float bv = be[gc];
#pragma unroll
        for (int r = 0; r < 4; ++r) {
          float h = acc[ti][tj][r] + bv;
          float g = 0.5f * h * (1.0f + erff(h * 0.70710678118654752f));
          Hout[(size_t)(gr + r) * ND + gc] = f2bf(g);
        }
      }
    }
  } else {
    const float* be = bias + (size_t)e * ND;
#pragma unroll
    for (int ti = 0; ti < 4; ++ti) {
      int pr = row0 + wm * 64 + ti * 16 + quad * 4;
#pragma unroll
      for (int r = 0; r < 4; ++r) {
        int p = pr + r;
        int tok = rows[p];
        float wt = wpos[p];
#pragma unroll
        for (int tj = 0; tj < 4; ++tj) {
          int gc = n0 + wn * 64 + tj * 16 + mlow;
          float val = wt * (acc[ti][tj][r] + be[gc]);
          atomicAdd(Oout + (size_t)tok * OUT_DIM + gc, val);
        }
      }
    }
  }
}

extern "C" void kernel_launch(void* const* d_in, const int* in_sizes, int n_in,
                              void* d_out, int out_size, void* d_ws, size_t ws_size,
                              hipStream_t stream) {
  const float* x      = (const float*)d_in[0];
  const float* gate_w = (const float*)d_in[1];
  const float* gate_b = (const float*)d_in[2];
  const float* w1     = (const float*)d_in[3];
  const float* b1     = (const float*)d_in[4];
  const float* w2     = (const float*)d_in[5];
  const float* b2     = (const float*)d_in[6];
  float* out = (float*)d_out;
  char* ws = (char*)d_ws;

  int*   cnt    = (int*)(ws + WS_CNT);
  int*   cursor = (int*)(ws + WS_CURSOR);
  int*   tkidx  = (int*)(ws + WS_TKIDX);
  float* tkw    = (float*)(ws + WS_TKW);
  int*   rows   = (int*)(ws + WS_ROWS);
  float* wpos   = (float*)(ws + WS_WPOS);
  short* w1t    = (short*)(ws + WS_W1T);
  short* w2t    = (short*)(ws + WS_W2T);
  short* xg     = (short*)(ws + WS_XG);
  short* h      = (short*)(ws + WS_H);

  hipMemsetAsync(ws, 0, 1280, stream);                                   // cnt+cursor
  hipMemsetAsync(d_out, 0, (size_t)out_size * sizeof(float), stream);    // out accumulated by atomics

  front_kernel<<<9216, 256, 0, stream>>>(w1, w1t, w2, w2t, x, gate_w, gate_b, tkidx, tkw, cnt);

  rank_kernel<<<NPAIRS / 1024, 1024, 0, stream>>>(tkidx, tkw, cnt, cursor, rows, wpos,
                                                  out + (size_t)B_TOKENS * OUT_DIM);

  copy_kernel<<<MAX_ROWS / 4, 256, 0, stream>>>(x, rows, cnt, xg);

  moe_gemm<IN_DIM, HID_DIM, 0><<<dim3(HID_DIM / 128, MAX_RB), 256, 0, stream>>>(
      xg, w1t, b1, cnt, rows, nullptr, h, nullptr);

  moe_gemm<HID_DIM, OUT_DIM, 1><<<dim3(OUT_DIM / 128, MAX_RB), 256, 0, stream>>>(
      h, w2t, b2, cnt, rows, wpos, nullptr, out);
}